// Round 10
// baseline (894.541 us; speedup 1.0000x reference)
//
#include <hip/hip_runtime.h>
#include <hip/hip_bf16.h>

#define BB 64
#define NN 50
#define TT 30
#define EE 300
#define FN 400
#define AA 200
#define GG 400

typedef __attribute__((ext_vector_type(8))) short bf16x8;
typedef __attribute__((ext_vector_type(4))) float f32x4;

__device__ inline ushort f2bf(float x) {
  __hip_bfloat16 b = __float2bfloat16(x);
  return *(ushort*)&b;
}

// ---------------------------------------------------------------------------
// K_PREP_ALL: all one-time weight repacks in a single launch.
// segments: Wpack | WT2 | vT | q/vb | Wih_bf | h0-init
// ---------------------------------------------------------------------------
__global__ void k_prep_all(
    const float* __restrict__ Whh, const float* __restrict__ cw,
    const float* __restrict__ v, const float* __restrict__ q,
    const float* __restrict__ vb, const float* __restrict__ Wih,
    const int* __restrict__ user_id, const float* __restrict__ user_emb,
    float* __restrict__ Wpack, __hip_bfloat16* __restrict__ WT2,
    __hip_bfloat16* __restrict__ vT, float* __restrict__ qp,
    float* __restrict__ vbp, __hip_bfloat16* __restrict__ Wih_bf,
    float* __restrict__ h0)
{
  int i = blockIdx.x * 256 + threadIdx.x;
  if (i < 480000) {                      // Wpack [8][400][150] fp32
    int jl = i % 150;
    int g = (i / 150) % 400;
    int gc = i / 60000;
    int gate = jl / 50, gl = jl - gate * 50;
    int j = gate * 400 + gc * 50 + gl;
    Wpack[i] = Whh[j * 400 + g];
  } else if (i < 910080) {               // WT2 bf16 [30 s][448 f][32 kk]
    int k = i - 480000;
    int kk = k & 31, f = (k >> 5) % 448, s = k / (448 * 32);
    int ko = s / 10, e = (s - ko * 10) * 32 + kk;
    float val = (f < FN && e < EE) ? cw[(ko * EE + e) * FN + f] : 0.f;
    WT2[k] = __float2bfloat16(val);
  } else if (i < 1003264) {              // vT bf16 [224 a][416 f]
    int k = i - 910080;
    int a = k / 416, f = k % 416;
    vT[k] = __float2bfloat16((a < AA && f < FN) ? v[f * AA + a] : 0.f);
  } else if (i < 1003488) {              // qp / vbp
    int k = i - 1003264;
    qp[k]  = k < AA ? q[k]  : 0.f;
    vbp[k] = k < AA ? vb[k] : 0.f;
  } else if (i < 1562592) {              // Wih_bf [1344 j][416 f]
    int k = i - 1003488;
    int j = k / 416, f = k % 416;
    Wih_bf[k] = __float2bfloat16((j < 1200 && f < FN) ? Wih[j * 400 + f] : 0.f);
  } else if (i < 1588192) {              // h0 = user_emb[user_id]
    int k = i - 1562592;
    int b = k / GG, g = k - b * GG;
    h0[k] = user_emb[(size_t)user_id[b] * GG + g];
  }
}

// ---------------------------------------------------------------------------
// K_CONV v3: barrier-free MFMA conv, register-balanced.
// Block = 2 titles, 512 thr / 8 waves: wave = (ti = wid>>2, wn = wid&3).
// acc[2][7] = 56 VGPR/lane -> room to pipeline the 7 B-fragment L2 loads.
// Emb gathered DIRECTLY from fp32 word_emb (bf16 cvt in-kernel), resident in
// LDS E[2][34][340] (stride 340 ushorts: start banks 10*l15 mod 32 distinct).
// B fragments stream from L2-resident WT2[30][448][32] (1KB coalesced/wave;
// ti-sibling waves share via L1). No barriers in the 30-step K-loop.
// ---------------------------------------------------------------------------
__global__ __launch_bounds__(512, 4) void k_conv(
    const int* __restrict__ title, const float* __restrict__ word_emb,
    const __hip_bfloat16* __restrict__ WT2, const float* __restrict__ conv_b,
    __hip_bfloat16* __restrict__ C)
{
  __shared__ __align__(16) ushort E[2][34][340];
  __shared__ int words[60];
  const int g = blockIdx.x;       // titles 2g, 2g+1
  const int tid = threadIdx.x;
  const int lane = tid & 63, wid = tid >> 6;
  const int ti = wid >> 2, wn = wid & 3;
  const int l15 = lane & 15, l4 = lane >> 4;

  if (tid < 60) words[tid] = title[g * 60 + tid];
  // zero all of E (covers conv padding slots + col tail 300..339)
  for (int idx = tid; idx < 2890; idx += 512)
    *(uint4*)((ushort*)E + idx * 8) = make_uint4(0u, 0u, 0u, 0u);
  __syncthreads();
  // stage 60 emb rows: fp32 -> bf16, slots 1..30
  for (int idx = tid; idx < 4500; idx += 512) {
    int row = idx / 75, ch = idx - row * 75;
    int tt = row / 30, w = row - tt * 30;
    float4 v4 = *(const float4*)(word_emb + (size_t)words[row] * EE + ch * 4);
    ushort4 u4 = make_ushort4(f2bf(v4.x), f2bf(v4.y), f2bf(v4.z), f2bf(v4.w));
    *(ushort4*)(&E[tt][w + 1][ch * 4]) = u4;
  }
  __syncthreads();

  f32x4 acc[2][7];
#pragma unroll
  for (int nt = 0; nt < 7; ++nt) {
    int f = wn * 112 + nt * 16 + l15;
    float bj = (f < FN) ? conv_b[f] : 0.f;
#pragma unroll
    for (int mt = 0; mt < 2; ++mt) {
      acc[mt][nt][0] = bj; acc[mt][nt][1] = bj;
      acc[mt][nt][2] = bj; acc[mt][nt][3] = bj;
    }
  }

  const ushort* Bbase = (const ushort*)WT2 + (size_t)(wn * 112 + l15) * 32 + l4 * 8;

#pragma unroll
  for (int ko = 0; ko < 3; ++ko) {
#pragma unroll
    for (int ks = 0; ks < 10; ++ks) {
      const int s = ko * 10 + ks;
      bf16x8 bq[7];
#pragma unroll
      for (int nt = 0; nt < 7; ++nt)
        bq[nt] = *(const bf16x8*)(Bbase + (size_t)s * 14336 + nt * 512);
      bf16x8 af[2];
#pragma unroll
      for (int mt = 0; mt < 2; ++mt)
        af[mt] = *(const bf16x8*)(&E[ti][mt * 16 + l15 + ko][ks * 32 + l4 * 8]);
#pragma unroll
      for (int nt = 0; nt < 7; ++nt)
#pragma unroll
        for (int mt = 0; mt < 2; ++mt)
          acc[mt][nt] = __builtin_amdgcn_mfma_f32_16x16x32_bf16(af[mt], bq[nt], acc[mt][nt], 0, 0, 0);
    }
  }

  // epilogue: ReLU + store C [3200*30][416] bf16
#pragma unroll
  for (int mt = 0; mt < 2; ++mt) {
    int tb = mt * 16 + l4 * 4;
#pragma unroll
    for (int nt = 0; nt < 7; ++nt) {
      int f = wn * 112 + nt * 16 + l15;
      if (f < 416) {
#pragma unroll
        for (int r = 0; r < 4; ++r) {
          int t = tb + r;
          if (t < TT) {
            float vv = fmaxf(acc[mt][nt][r], 0.f);
            C[((size_t)(g * 2 + ti) * 30 + t) * 416 + f] = __float2bfloat16(vv);
          }
        }
      }
    }
  }
}

// ---------------------------------------------------------------------------
// K_ATTN: score[r] = sum_a tanh( (C[r,:] @ v[:,a]) + vb[a] ) * q[a]
// ---------------------------------------------------------------------------
__global__ __launch_bounds__(512) void k_attn(
    const __hip_bfloat16* __restrict__ C, const __hip_bfloat16* __restrict__ vT,
    const float* __restrict__ vbp, const float* __restrict__ qp,
    float* __restrict__ score)
{
  __shared__ __align__(16) ushort Clds[256 * 40];
  __shared__ __align__(16) ushort Vlds[224 * 40];
  __shared__ float sred[2][256];
  const int tid = threadIdx.x;
  const int lane = tid & 63, wid = tid >> 6;
  const int wm = wid >> 1, wn = wid & 1;
  const int l15 = lane & 15, l4 = lane >> 4;
  const size_t row0 = (size_t)blockIdx.x * 256;

  f32x4 acc[4][7];
  float ql[7];
#pragma unroll
  for (int nt = 0; nt < 7; ++nt) {
    int a = wn * 112 + nt * 16 + l15;
    ql[nt] = qp[a];
    float vbv = vbp[a];
#pragma unroll
    for (int mt = 0; mt < 4; ++mt) {
      acc[mt][nt][0] = vbv; acc[mt][nt][1] = vbv;
      acc[mt][nt][2] = vbv; acc[mt][nt][3] = vbv;
    }
  }

  for (int ks = 0; ks < 13; ++ks) {
    for (int idx = tid; idx < 1024; idx += 512) {
      int r = idx >> 2, c = idx & 3;
      *(uint4*)(&Clds[r * 40 + c * 8]) =
          *(const uint4*)((const ushort*)C + (row0 + r) * 416 + ks * 32 + c * 8);
    }
    for (int idx = tid; idx < 896; idx += 512) {
      int a = idx >> 2, c = idx & 3;
      *(uint4*)(&Vlds[a * 40 + c * 8]) =
          *(const uint4*)((const ushort*)vT + a * 416 + ks * 32 + c * 8);
    }
    __syncthreads();
    bf16x8 cf[4];
#pragma unroll
    for (int mt = 0; mt < 4; ++mt)
      cf[mt] = *(const bf16x8*)(&Clds[(wm * 64 + mt * 16 + l15) * 40 + l4 * 8]);
#pragma unroll
    for (int nt = 0; nt < 7; ++nt) {
      bf16x8 vf = *(const bf16x8*)(&Vlds[(wn * 112 + nt * 16 + l15) * 40 + l4 * 8]);
#pragma unroll
      for (int mt = 0; mt < 4; ++mt)
        acc[mt][nt] = __builtin_amdgcn_mfma_f32_16x16x32_bf16(cf[mt], vf, acc[mt][nt], 0, 0, 0);
    }
    __syncthreads();
  }

  float sums[4][4];
#pragma unroll
  for (int mt = 0; mt < 4; ++mt)
#pragma unroll
    for (int r = 0; r < 4; ++r) sums[mt][r] = 0.f;
#pragma unroll
  for (int mt = 0; mt < 4; ++mt)
#pragma unroll
    for (int nt = 0; nt < 7; ++nt)
#pragma unroll
      for (int r = 0; r < 4; ++r)
        sums[mt][r] += tanhf(acc[mt][nt][r]) * ql[nt];
#pragma unroll
  for (int mask = 1; mask < 16; mask <<= 1)
#pragma unroll
    for (int mt = 0; mt < 4; ++mt)
#pragma unroll
      for (int r = 0; r < 4; ++r)
        sums[mt][r] += __shfl_xor(sums[mt][r], mask);

  float outv = 0.f;
#pragma unroll
  for (int mt = 0; mt < 4; ++mt)
#pragma unroll
    for (int r = 0; r < 4; ++r)
      if (l15 == mt * 4 + r) outv = sums[mt][r];
  sred[wn][wm * 64 + (l15 >> 2) * 16 + l4 * 4 + (l15 & 3)] = outv;
  __syncthreads();
  if (tid < 256) score[row0 + tid] = sred[0][tid] + sred[1][tid];
}

// ---------------------------------------------------------------------------
// K2: softmax over the N (titles) axis, per (b,t).
// ---------------------------------------------------------------------------
__global__ void k2_softmax_n(const float* __restrict__ score, float* __restrict__ alpha) {
  int i = blockIdx.x * 256 + threadIdx.x;
  if (i >= BB * TT) return;
  int b = i / TT, t = i - b * TT;
  int base = b * (NN * TT) + t;
  float m = -1e30f;
  for (int n = 0; n < NN; ++n) m = fmaxf(m, score[base + n * TT]);
  float s = 0.f;
  for (int n = 0; n < NN; ++n) s += __expf(score[base + n * TT] - m);
  float inv = 1.f / s;
  for (int n = 0; n < NN; ++n)
    alpha[base + n * TT] = __expf(score[base + n * TT] - m) * inv;
}

// ---------------------------------------------------------------------------
// K3: e[bn,f] = sum_t alpha[bn,t] * C[bn,t,f]  -> bf16 [3200][416] padded
// ---------------------------------------------------------------------------
__global__ __launch_bounds__(256) void k3_wsum(
    const float* __restrict__ alpha, const __hip_bfloat16* __restrict__ C,
    __hip_bfloat16* __restrict__ Ebf) {
  __shared__ float al[TT];
  const int bn = blockIdx.x;
  const int tid = threadIdx.x;
  if (tid < TT) al[tid] = alpha[bn * TT + tid];
  __syncthreads();
  for (int f = tid; f < 416; f += 256) {
    float s = 0.f;
    if (f < FN) {
#pragma unroll
      for (int t = 0; t < TT; ++t)
        s = fmaf(al[t], __bfloat162float(C[((size_t)bn * TT + t) * 416 + f]), s);
    }
    Ebf[(size_t)bn * 416 + f] = __float2bfloat16(s);
  }
}

// ---------------------------------------------------------------------------
// K4: gx = e @ W_ih^T + b_ih via bf16 MFMA. M=3200, N=1344(pad), K=416.
// ---------------------------------------------------------------------------
__global__ __launch_bounds__(512) void k4_gx_mfma(
    const __hip_bfloat16* __restrict__ Ebf,   // [3200][416]
    const __hip_bfloat16* __restrict__ Wih,   // [1344][416]
    const float* __restrict__ b_ih,           // [1200]
    float* __restrict__ gx)                   // [3200][1200]
{
  __shared__ __align__(16) ushort Alds[128 * 40];
  __shared__ __align__(16) ushort Blds[448 * 40];
  const int tid = threadIdx.x;
  const int lane = tid & 63, wid = tid >> 6;
  const int wm = wid >> 2, wn = wid & 3;
  const int l15 = lane & 15, l4 = lane >> 4;
  const int mb = blockIdx.x / 3;
  const int nb = blockIdx.x - mb * 3;
  const int row0 = mb * 128;
  const int n0 = nb * 448;

  f32x4 acc[4][7];
#pragma unroll
  for (int nt = 0; nt < 7; ++nt) {
    int j = n0 + wn * 112 + nt * 16 + l15;
    float bj = (j < 1200) ? b_ih[j] : 0.f;
#pragma unroll
    for (int mt = 0; mt < 4; ++mt) {
      acc[mt][nt][0] = bj; acc[mt][nt][1] = bj;
      acc[mt][nt][2] = bj; acc[mt][nt][3] = bj;
    }
  }

  const int ar = tid >> 2, ac = tid & 3;
  for (int ks = 0; ks < 13; ++ks) {
    *(uint4*)(&Alds[ar * 40 + ac * 8]) =
        *(const uint4*)((const ushort*)Ebf + (size_t)(row0 + ar) * 416 + ks * 32 + ac * 8);
    for (int idx = tid; idx < 1792; idx += 512) {
      int r = idx >> 2, c = idx & 3;
      *(uint4*)(&Blds[r * 40 + c * 8]) =
          *(const uint4*)((const ushort*)Wih + (size_t)(n0 + r) * 416 + ks * 32 + c * 8);
    }
    __syncthreads();
    bf16x8 af[4];
#pragma unroll
    for (int mt = 0; mt < 4; ++mt)
      af[mt] = *(const bf16x8*)(&Alds[(wm * 64 + mt * 16 + l15) * 40 + l4 * 8]);
#pragma unroll
    for (int nt = 0; nt < 7; ++nt) {
      bf16x8 bfr = *(const bf16x8*)(&Blds[(wn * 112 + nt * 16 + l15) * 40 + l4 * 8]);
#pragma unroll
      for (int mt = 0; mt < 4; ++mt)
        acc[mt][nt] = __builtin_amdgcn_mfma_f32_16x16x32_bf16(af[mt], bfr, acc[mt][nt], 0, 0, 0);
    }
    __syncthreads();
  }

#pragma unroll
  for (int mt = 0; mt < 4; ++mt) {
    int row = row0 + wm * 64 + mt * 16 + l4 * 4;
#pragma unroll
    for (int nt = 0; nt < 7; ++nt) {
      int j = n0 + wn * 112 + nt * 16 + l15;
      if (j < 1200) {
#pragma unroll
        for (int r = 0; r < 4; ++r)
          gx[(size_t)(row + r) * 1200 + j] = acc[mt][nt][r];
      }
    }
  }
}

// ---------------------------------------------------------------------------
// GRU: 50-launch chain (grid.sync measured 7x slower on this chip — per-XCD
// L2 non-coherence makes device-scope fences cost ~35us/step at 256 blocks).
// GEMV uses 4 independent FMA chains (dep-chain 400->200) for ILP.
// Final step also writes `out` directly (k5_out folded in).
// ---------------------------------------------------------------------------
__global__ __launch_bounds__(256) void k5_step(
    const float* __restrict__ h_prev, float* __restrict__ h_next,
    const float* __restrict__ Wpack, const float* __restrict__ b_hh,
    const float* __restrict__ gx, const int* __restrict__ hist_len,
    float* __restrict__ out, int step)
{
  const int gc = blockIdx.x & 7;
  const int bg = blockIdx.x >> 3;
  const int tid = threadIdx.x;
  __shared__ float hl[2][GG];
  __shared__ float ghl[2][3][50];

  for (int i = tid; i < 2 * GG; i += 256) {
    int b = i / GG, g = i - b * GG;
    hl[b][g] = h_prev[(2 * bg + b) * GG + g];
  }
  __syncthreads();

  if (tid < 150) {
    float a00 = 0.f, a01 = 0.f, a10 = 0.f, a11 = 0.f;
    const float* wp = Wpack + (size_t)gc * 60000 + tid;
#pragma unroll 4
    for (int g = 0; g < 200; ++g) {
      float w0 = wp[g * 150];
      float w1 = wp[(g + 200) * 150];
      a00 = fmaf(hl[0][g], w0, a00);
      a10 = fmaf(hl[1][g], w0, a10);
      a01 = fmaf(hl[0][g + 200], w1, a01);
      a11 = fmaf(hl[1][g + 200], w1, a11);
    }
    int gate = tid / 50, gl = tid - gate * 50;
    float bb = b_hh[gate * 400 + gc * 50 + gl];
    ghl[0][gate][gl] = a00 + a01 + bb;
    ghl[1][gate][gl] = a10 + a11 + bb;
  }
  __syncthreads();

  if (tid < 100) {
    int b = tid / 50, gl = tid - (tid / 50) * 50;
    int babs = 2 * bg + b;
    int g = gc * 50 + gl;
    const float* gxp = gx + ((size_t)babs * NN + step) * 1200;
    float xr = gxp[g], xz = gxp[400 + g], xn = gxp[800 + g];
    float hr = ghl[b][0][gl], hz = ghl[b][1][gl], hn = ghl[b][2][gl];
    float r = 1.f / (1.f + __expf(-(xr + hr)));
    float z = 1.f / (1.f + __expf(-(xz + hz)));
    float nv = tanhf(xn + r * hn);
    float hold = hl[b][g];
    float hnew = (1.f - z) * nv + z * hold;
    float hres = (step < hist_len[babs]) ? hnew : hold;
    h_next[babs * GG + g] = hres;
    if (step == NN - 1) out[babs * GG + g] = hres;
  }
}

// ---------------------------------------------------------------------------
extern "C" void kernel_launch(void* const* d_in, const int* in_sizes, int n_in,
                              void* d_out, int out_size, void* d_ws, size_t ws_size,
                              hipStream_t stream) {
  const int*   user_id   = (const int*)d_in[0];
  const int*   title     = (const int*)d_in[1];
  const int*   hist_len  = (const int*)d_in[2];
  const float* word_emb  = (const float*)d_in[3];
  const float* conv_w    = (const float*)d_in[4];
  const float* conv_b    = (const float*)d_in[5];
  const float* v         = (const float*)d_in[6];
  const float* vb        = (const float*)d_in[7];
  const float* q         = (const float*)d_in[8];
  const float* user_emb  = (const float*)d_in[9];
  const float* W_ih      = (const float*)d_in[10];
  const float* W_hh      = (const float*)d_in[11];
  const float* b_ih      = (const float*)d_in[12];
  const float* b_hh      = (const float*)d_in[13];
  float* out = (float*)d_out;

  char* ws = (char*)d_ws;
  size_t off = 0;
  auto take = [&](size_t bytes) {
    char* p = ws + off;
    off = (off + bytes + 255) & ~(size_t)255;
    return p;
  };
  __hip_bfloat16* C      = (__hip_bfloat16*)take((size_t)BB * NN * TT * 416 * 2);  // 79.9MB
  float* score  = (float*)take((size_t)BB * NN * TT * 4);
  float* alpha  = (float*)take((size_t)BB * NN * TT * 4);
  __hip_bfloat16* Ebf    = (__hip_bfloat16*)take((size_t)BB * NN * 416 * 2);
  __hip_bfloat16* Wih_bf = (__hip_bfloat16*)take((size_t)1344 * 416 * 2);
  float* Wpack  = (float*)take((size_t)8 * 400 * 150 * 4);
  float* gx     = (float*)take((size_t)BB * NN * 1200 * 4);
  float* h0     = (float*)take((size_t)BB * GG * 4);
  float* h1     = (float*)take((size_t)BB * GG * 4);
  __hip_bfloat16* WT2    = (__hip_bfloat16*)take((size_t)30 * 448 * 32 * 2);      // 860KB
  __hip_bfloat16* vT     = (__hip_bfloat16*)take((size_t)224 * 416 * 2);
  float* qp     = (float*)take(224 * 4);
  float* vbp    = (float*)take(224 * 4);
  (void)ws_size;

  k_prep_all<<<6204, 256, 0, stream>>>(W_hh, conv_w, v, q, vb, W_ih, user_id,
                                       user_emb, Wpack, WT2, vT, qp, vbp,
                                       Wih_bf, h0);

  k_conv<<<BB * NN / 2, 512, 0, stream>>>(title, word_emb, WT2, conv_b, C);
  k_attn<<<BB * NN * TT / 256, 512, 0, stream>>>(C, vT, vbp, qp, score);
  k2_softmax_n<<<(BB * TT + 255) / 256, 256, 0, stream>>>(score, alpha);
  k3_wsum<<<BB * NN, 256, 0, stream>>>(alpha, C, Ebf);
  k4_gx_mfma<<<75, 512, 0, stream>>>(Ebf, Wih_bf, b_ih, gx);

  float* hbuf[2] = {h0, h1};
  for (int step = 0; step < NN; ++step) {
    k5_step<<<256, 256, 0, stream>>>(hbuf[step & 1], hbuf[(step + 1) & 1],
                                     Wpack, b_hh, gx, hist_len, out, step);
  }
}

// Round 11
// 882.047 us; speedup vs baseline: 1.0142x; 1.0142x over previous
//
#include <hip/hip_runtime.h>
#include <hip/hip_bf16.h>

#define BB 64
#define NN 50
#define TT 30
#define EE 300
#define FN 400
#define AA 200
#define GG 400

typedef __attribute__((ext_vector_type(8))) short bf16x8;
typedef __attribute__((ext_vector_type(4))) float f32x4;

__device__ inline ushort f2bf(float x) {
  __hip_bfloat16 b = __float2bfloat16(x);
  return *(ushort*)&b;
}

// ---------------------------------------------------------------------------
// K_PREP_ALL: all one-time weight repacks in a single launch.
// segments: Wpack | WT2 | vT2 | q/vb | Wih_bf | h0-init
// ---------------------------------------------------------------------------
__global__ void k_prep_all(
    const float* __restrict__ Whh, const float* __restrict__ cw,
    const float* __restrict__ v, const float* __restrict__ q,
    const float* __restrict__ vb, const float* __restrict__ Wih,
    const int* __restrict__ user_id, const float* __restrict__ user_emb,
    float* __restrict__ Wpack, __hip_bfloat16* __restrict__ WT2,
    __hip_bfloat16* __restrict__ vT2, float* __restrict__ qp,
    float* __restrict__ vbp, __hip_bfloat16* __restrict__ Wih_bf,
    float* __restrict__ h0)
{
  int i = blockIdx.x * 256 + threadIdx.x;
  if (i < 480000) {                      // Wpack [8][400][150] fp32
    int jl = i % 150;
    int g = (i / 150) % 400;
    int gc = i / 60000;
    int gate = jl / 50, gl = jl - gate * 50;
    int j = gate * 400 + gc * 50 + gl;
    Wpack[i] = Whh[j * 400 + g];
  } else if (i < 910080) {               // WT2 bf16 [30 s][448 f][32 kk]
    int k = i - 480000;
    int kk = k & 31, f = (k >> 5) % 448, s = k / (448 * 32);
    int ko = s / 10, e = (s - ko * 10) * 32 + kk;
    float val = (f < FN && e < EE) ? cw[(ko * EE + e) * FN + f] : 0.f;
    WT2[k] = __float2bfloat16(val);
  } else if (i < 1003264) {              // vT2 bf16 [13 ks][224 a][32 kk]
    int k = i - 910080;
    int kk = k & 31, a = (k >> 5) % 224, ks = k / (224 * 32);
    int e = ks * 32 + kk;
    float val = (a < AA && e < FN) ? v[e * AA + a] : 0.f;
    vT2[k] = __float2bfloat16(val);
  } else if (i < 1003488) {              // qp / vbp
    int k = i - 1003264;
    qp[k]  = k < AA ? q[k]  : 0.f;
    vbp[k] = k < AA ? vb[k] : 0.f;
  } else if (i < 1562592) {              // Wih_bf [1344 j][416 f]
    int k = i - 1003488;
    int j = k / 416, f = k % 416;
    Wih_bf[k] = __float2bfloat16((j < 1200 && f < FN) ? Wih[j * 400 + f] : 0.f);
  } else if (i < 1588192) {              // h0 = user_emb[user_id]
    int k = i - 1562592;
    int b = k / GG, g = k - b * GG;
    h0[k] = user_emb[(size_t)user_id[b] * GG + g];
  }
}

// ---------------------------------------------------------------------------
// K_CONV v4: barrier-free MFMA conv, latency-hidden.
// Block = 2 titles, 256 thr / 4 waves (wn = f-quarter). acc[4][7] per wave
// (28 MFMA per 7-fragment B-load group — v2's proven ratio). B fragments
// double-buffered in registers: step s+1's loads issue while step s's MFMAs
// run (2-step unrolled loop, statically-indexed buffers). Emb gathered
// directly from fp32 word_emb into LDS E[2][34][344] (stride 344 ushorts =
// 688B: 16B-aligned rows -> true ds_read_b128; 8 start banks, ~2-way max).
// ---------------------------------------------------------------------------
__global__ __launch_bounds__(256, 2) void k_conv(
    const int* __restrict__ title, const float* __restrict__ word_emb,
    const __hip_bfloat16* __restrict__ WT2, const float* __restrict__ conv_b,
    __hip_bfloat16* __restrict__ C)
{
  __shared__ __align__(16) ushort E[2][34][344];
  __shared__ int words[60];
  const int g = blockIdx.x;       // titles 2g, 2g+1
  const int tid = threadIdx.x;
  const int lane = tid & 63, wn = tid >> 6;
  const int l15 = lane & 15, l4 = lane >> 4;

  if (tid < 60) words[tid] = title[g * 60 + tid];
  // zero all of E (conv padding slots 0/31/32/33 + col tail 300..343)
  for (int idx = tid; idx < 2924; idx += 256)
    *(uint4*)((ushort*)E + idx * 8) = make_uint4(0u, 0u, 0u, 0u);
  __syncthreads();
  // stage 60 emb rows: fp32 -> bf16, slots 1..30
  for (int idx = tid; idx < 4500; idx += 256) {
    int row = idx / 75, ch = idx - row * 75;
    int tt = row / 30, w = row - tt * 30;
    float4 v4 = *(const float4*)(word_emb + (size_t)words[row] * EE + ch * 4);
    ushort4 u4 = make_ushort4(f2bf(v4.x), f2bf(v4.y), f2bf(v4.z), f2bf(v4.w));
    *(ushort4*)(&E[tt][w + 1][ch * 4]) = u4;
  }
  __syncthreads();

  f32x4 acc[4][7];
#pragma unroll
  for (int nt = 0; nt < 7; ++nt) {
    int f = wn * 112 + nt * 16 + l15;
    float bj = (f < FN) ? conv_b[f] : 0.f;
#pragma unroll
    for (int mt = 0; mt < 4; ++mt) {
      acc[mt][nt][0] = bj; acc[mt][nt][1] = bj;
      acc[mt][nt][2] = bj; acc[mt][nt][3] = bj;
    }
  }

  const ushort* Bbase = (const ushort*)WT2 + (size_t)(wn * 112 + l15) * 32 + l4 * 8;

#define LOADB(dst, s) {                                                        \
    const ushort* p_ = Bbase + (size_t)(s) * 14336;                            \
    _Pragma("unroll")                                                          \
    for (int nt = 0; nt < 7; ++nt) dst[nt] = *(const bf16x8*)(p_ + nt * 512);  \
  }
#define DOMFMA(bq, s) {                                                        \
    const int ko_ = (s) / 10, ks_ = (s) % 10;                                  \
    bf16x8 af_[4];                                                             \
    _Pragma("unroll")                                                          \
    for (int mt = 0; mt < 4; ++mt)                                             \
      af_[mt] = *(const bf16x8*)(&E[mt >> 1][(mt & 1) * 16 + l15 + ko_]        \
                                   [ks_ * 32 + l4 * 8]);                       \
    _Pragma("unroll")                                                          \
    for (int nt = 0; nt < 7; ++nt)                                             \
      _Pragma("unroll")                                                        \
      for (int mt = 0; mt < 4; ++mt)                                           \
        acc[mt][nt] = __builtin_amdgcn_mfma_f32_16x16x32_bf16(                 \
            af_[mt], bq[nt], acc[mt][nt], 0, 0, 0);                            \
  }

  bf16x8 bqA[7], bqB[7];
  LOADB(bqA, 0);
#pragma unroll
  for (int it = 0; it < 15; ++it) {
    const int s0 = it * 2;
    LOADB(bqB, s0 + 1);          // prefetch odd step
    DOMFMA(bqA, s0);
    if (it < 14) LOADB(bqA, s0 + 2);  // prefetch next even step
    DOMFMA(bqB, s0 + 1);
  }
#undef LOADB
#undef DOMFMA

  // epilogue: ReLU + store C [3200*30][416] bf16
#pragma unroll
  for (int mt = 0; mt < 4; ++mt) {
    const int ti = mt >> 1;
    const int tb = (mt & 1) * 16 + l4 * 4;
#pragma unroll
    for (int nt = 0; nt < 7; ++nt) {
      int f = wn * 112 + nt * 16 + l15;
      if (f < 416) {
#pragma unroll
        for (int r = 0; r < 4; ++r) {
          int t = tb + r;
          if (t < TT) {
            float vv = fmaxf(acc[mt][nt][r], 0.f);
            C[((size_t)(g * 2 + ti) * 30 + t) * 416 + f] = __float2bfloat16(vv);
          }
        }
      }
    }
  }
}

// ---------------------------------------------------------------------------
// K_ATTN: score[r] = sum_a tanh( (C[r,:] @ v[:,a]) + vb[a] ) * q[a]
// V fragments now load DIRECTLY from L2-resident vT2[13][224][32] (1KB
// coalesced per load, issued at loop top) — Vlds staging removed.
// ---------------------------------------------------------------------------
__global__ __launch_bounds__(512) void k_attn(
    const __hip_bfloat16* __restrict__ C, const __hip_bfloat16* __restrict__ vT2,
    const float* __restrict__ vbp, const float* __restrict__ qp,
    float* __restrict__ score)
{
  __shared__ __align__(16) ushort Clds[256 * 40];
  __shared__ float sred[2][256];
  const int tid = threadIdx.x;
  const int lane = tid & 63, wid = tid >> 6;
  const int wm = wid >> 1, wn = wid & 1;
  const int l15 = lane & 15, l4 = lane >> 4;
  const size_t row0 = (size_t)blockIdx.x * 256;

  f32x4 acc[4][7];
  float ql[7];
#pragma unroll
  for (int nt = 0; nt < 7; ++nt) {
    int a = wn * 112 + nt * 16 + l15;
    ql[nt] = qp[a];
    float vbv = vbp[a];
#pragma unroll
    for (int mt = 0; mt < 4; ++mt) {
      acc[mt][nt][0] = vbv; acc[mt][nt][1] = vbv;
      acc[mt][nt][2] = vbv; acc[mt][nt][3] = vbv;
    }
  }

  const ushort* Vbase = (const ushort*)vT2 + (size_t)(wn * 112 + l15) * 32 + l4 * 8;

  for (int ks = 0; ks < 13; ++ks) {
    // V fragments direct from L2 (no LDS)
    bf16x8 vf[7];
#pragma unroll
    for (int nt = 0; nt < 7; ++nt)
      vf[nt] = *(const bf16x8*)(Vbase + ((size_t)ks * 224 + nt * 16) * 32);
    // C tile through LDS (coalesced stage)
    for (int idx = tid; idx < 1024; idx += 512) {
      int r = idx >> 2, c = idx & 3;
      *(uint4*)(&Clds[r * 40 + c * 8]) =
          *(const uint4*)((const ushort*)C + (row0 + r) * 416 + ks * 32 + c * 8);
    }
    __syncthreads();
    bf16x8 cf[4];
#pragma unroll
    for (int mt = 0; mt < 4; ++mt)
      cf[mt] = *(const bf16x8*)(&Clds[(wm * 64 + mt * 16 + l15) * 40 + l4 * 8]);
#pragma unroll
    for (int nt = 0; nt < 7; ++nt)
#pragma unroll
      for (int mt = 0; mt < 4; ++mt)
        acc[mt][nt] = __builtin_amdgcn_mfma_f32_16x16x32_bf16(cf[mt], vf[nt], acc[mt][nt], 0, 0, 0);
    __syncthreads();
  }

  float sums[4][4];
#pragma unroll
  for (int mt = 0; mt < 4; ++mt)
#pragma unroll
    for (int r = 0; r < 4; ++r) sums[mt][r] = 0.f;
#pragma unroll
  for (int mt = 0; mt < 4; ++mt)
#pragma unroll
    for (int nt = 0; nt < 7; ++nt)
#pragma unroll
      for (int r = 0; r < 4; ++r)
        sums[mt][r] += tanhf(acc[mt][nt][r]) * ql[nt];
#pragma unroll
  for (int mask = 1; mask < 16; mask <<= 1)
#pragma unroll
    for (int mt = 0; mt < 4; ++mt)
#pragma unroll
      for (int r = 0; r < 4; ++r)
        sums[mt][r] += __shfl_xor(sums[mt][r], mask);

  float outv = 0.f;
#pragma unroll
  for (int mt = 0; mt < 4; ++mt)
#pragma unroll
    for (int r = 0; r < 4; ++r)
      if (l15 == mt * 4 + r) outv = sums[mt][r];
  sred[wn][wm * 64 + (l15 >> 2) * 16 + l4 * 4 + (l15 & 3)] = outv;
  __syncthreads();
  if (tid < 256) score[row0 + tid] = sred[0][tid] + sred[1][tid];
}

// ---------------------------------------------------------------------------
// K2: softmax over the N (titles) axis, per (b,t).
// ---------------------------------------------------------------------------
__global__ void k2_softmax_n(const float* __restrict__ score, float* __restrict__ alpha) {
  int i = blockIdx.x * 256 + threadIdx.x;
  if (i >= BB * TT) return;
  int b = i / TT, t = i - b * TT;
  int base = b * (NN * TT) + t;
  float m = -1e30f;
  for (int n = 0; n < NN; ++n) m = fmaxf(m, score[base + n * TT]);
  float s = 0.f;
  for (int n = 0; n < NN; ++n) s += __expf(score[base + n * TT] - m);
  float inv = 1.f / s;
  for (int n = 0; n < NN; ++n)
    alpha[base + n * TT] = __expf(score[base + n * TT] - m) * inv;
}

// ---------------------------------------------------------------------------
// K3: e[bn,f] = sum_t alpha[bn,t] * C[bn,t,f]  -> bf16 [3200][416] padded
// ---------------------------------------------------------------------------
__global__ __launch_bounds__(256) void k3_wsum(
    const float* __restrict__ alpha, const __hip_bfloat16* __restrict__ C,
    __hip_bfloat16* __restrict__ Ebf) {
  __shared__ float al[TT];
  const int bn = blockIdx.x;
  const int tid = threadIdx.x;
  if (tid < TT) al[tid] = alpha[bn * TT + tid];
  __syncthreads();
  for (int f = tid; f < 416; f += 256) {
    float s = 0.f;
    if (f < FN) {
#pragma unroll
      for (int t = 0; t < TT; ++t)
        s = fmaf(al[t], __bfloat162float(C[((size_t)bn * TT + t) * 416 + f]), s);
    }
    Ebf[(size_t)bn * 416 + f] = __float2bfloat16(s);
  }
}

// ---------------------------------------------------------------------------
// K4: gx = e @ W_ih^T + b_ih via bf16 MFMA. M=3200, N=1344(pad), K=416.
// ---------------------------------------------------------------------------
__global__ __launch_bounds__(512) void k4_gx_mfma(
    const __hip_bfloat16* __restrict__ Ebf,   // [3200][416]
    const __hip_bfloat16* __restrict__ Wih,   // [1344][416]
    const float* __restrict__ b_ih,           // [1200]
    float* __restrict__ gx)                   // [3200][1200]
{
  __shared__ __align__(16) ushort Alds[128 * 40];
  __shared__ __align__(16) ushort Blds[448 * 40];
  const int tid = threadIdx.x;
  const int lane = tid & 63, wid = tid >> 6;
  const int wm = wid >> 2, wn = wid & 3;
  const int l15 = lane & 15, l4 = lane >> 4;
  const int mb = blockIdx.x / 3;
  const int nb = blockIdx.x - mb * 3;
  const int row0 = mb * 128;
  const int n0 = nb * 448;

  f32x4 acc[4][7];
#pragma unroll
  for (int nt = 0; nt < 7; ++nt) {
    int j = n0 + wn * 112 + nt * 16 + l15;
    float bj = (j < 1200) ? b_ih[j] : 0.f;
#pragma unroll
    for (int mt = 0; mt < 4; ++mt) {
      acc[mt][nt][0] = bj; acc[mt][nt][1] = bj;
      acc[mt][nt][2] = bj; acc[mt][nt][3] = bj;
    }
  }

  const int ar = tid >> 2, ac = tid & 3;
  for (int ks = 0; ks < 13; ++ks) {
    *(uint4*)(&Alds[ar * 40 + ac * 8]) =
        *(const uint4*)((const ushort*)Ebf + (size_t)(row0 + ar) * 416 + ks * 32 + ac * 8);
    for (int idx = tid; idx < 1792; idx += 512) {
      int r = idx >> 2, c = idx & 3;
      *(uint4*)(&Blds[r * 40 + c * 8]) =
          *(const uint4*)((const ushort*)Wih + (size_t)(n0 + r) * 416 + ks * 32 + c * 8);
    }
    __syncthreads();
    bf16x8 af[4];
#pragma unroll
    for (int mt = 0; mt < 4; ++mt)
      af[mt] = *(const bf16x8*)(&Alds[(wm * 64 + mt * 16 + l15) * 40 + l4 * 8]);
#pragma unroll
    for (int nt = 0; nt < 7; ++nt) {
      bf16x8 bfr = *(const bf16x8*)(&Blds[(wn * 112 + nt * 16 + l15) * 40 + l4 * 8]);
#pragma unroll
      for (int mt = 0; mt < 4; ++mt)
        acc[mt][nt] = __builtin_amdgcn_mfma_f32_16x16x32_bf16(af[mt], bfr, acc[mt][nt], 0, 0, 0);
    }
    __syncthreads();
  }

#pragma unroll
  for (int mt = 0; mt < 4; ++mt) {
    int row = row0 + wm * 64 + mt * 16 + l4 * 4;
#pragma unroll
    for (int nt = 0; nt < 7; ++nt) {
      int j = n0 + wn * 112 + nt * 16 + l15;
      if (j < 1200) {
#pragma unroll
        for (int r = 0; r < 4; ++r)
          gx[(size_t)(row + r) * 1200 + j] = acc[mt][nt][r];
      }
    }
  }
}

// ---------------------------------------------------------------------------
// GRU: 50-launch chain (grid.sync measured 7x slower on this chip — per-XCD
// L2 non-coherence makes device-scope fences cost ~35us/step at 256 blocks).
// GEMV uses 4 independent FMA chains; final step writes `out` directly.
// ---------------------------------------------------------------------------
__global__ __launch_bounds__(256) void k5_step(
    const float* __restrict__ h_prev, float* __restrict__ h_next,
    const float* __restrict__ Wpack, const float* __restrict__ b_hh,
    const float* __restrict__ gx, const int* __restrict__ hist_len,
    float* __restrict__ out, int step)
{
  const int gc = blockIdx.x & 7;
  const int bg = blockIdx.x >> 3;
  const int tid = threadIdx.x;
  __shared__ float hl[2][GG];
  __shared__ float ghl[2][3][50];

  for (int i = tid; i < 2 * GG; i += 256) {
    int b = i / GG, g = i - b * GG;
    hl[b][g] = h_prev[(2 * bg + b) * GG + g];
  }
  __syncthreads();

  if (tid < 150) {
    float a00 = 0.f, a01 = 0.f, a10 = 0.f, a11 = 0.f;
    const float* wp = Wpack + (size_t)gc * 60000 + tid;
#pragma unroll 4
    for (int g = 0; g < 200; ++g) {
      float w0 = wp[g * 150];
      float w1 = wp[(g + 200) * 150];
      a00 = fmaf(hl[0][g], w0, a00);
      a10 = fmaf(hl[1][g], w0, a10);
      a01 = fmaf(hl[0][g + 200], w1, a01);
      a11 = fmaf(hl[1][g + 200], w1, a11);
    }
    int gate = tid / 50, gl = tid - gate * 50;
    float bb = b_hh[gate * 400 + gc * 50 + gl];
    ghl[0][gate][gl] = a00 + a01 + bb;
    ghl[1][gate][gl] = a10 + a11 + bb;
  }
  __syncthreads();

  if (tid < 100) {
    int b = tid / 50, gl = tid - (tid / 50) * 50;
    int babs = 2 * bg + b;
    int g = gc * 50 + gl;
    const float* gxp = gx + ((size_t)babs * NN + step) * 1200;
    float xr = gxp[g], xz = gxp[400 + g], xn = gxp[800 + g];
    float hr = ghl[b][0][gl], hz = ghl[b][1][gl], hn = ghl[b][2][gl];
    float r = 1.f / (1.f + __expf(-(xr + hr)));
    float z = 1.f / (1.f + __expf(-(xz + hz)));
    float nv = tanhf(xn + r * hn);
    float hold = hl[b][g];
    float hnew = (1.f - z) * nv + z * hold;
    float hres = (step < hist_len[babs]) ? hnew : hold;
    h_next[babs * GG + g] = hres;
    if (step == NN - 1) out[babs * GG + g] = hres;
  }
}

// ---------------------------------------------------------------------------
extern "C" void kernel_launch(void* const* d_in, const int* in_sizes, int n_in,
                              void* d_out, int out_size, void* d_ws, size_t ws_size,
                              hipStream_t stream) {
  const int*   user_id   = (const int*)d_in[0];
  const int*   title     = (const int*)d_in[1];
  const int*   hist_len  = (const int*)d_in[2];
  const float* word_emb  = (const float*)d_in[3];
  const float* conv_w    = (const float*)d_in[4];
  const float* conv_b    = (const float*)d_in[5];
  const float* v         = (const float*)d_in[6];
  const float* vb        = (const float*)d_in[7];
  const float* q         = (const float*)d_in[8];
  const float* user_emb  = (const float*)d_in[9];
  const float* W_ih      = (const float*)d_in[10];
  const float* W_hh      = (const float*)d_in[11];
  const float* b_ih      = (const float*)d_in[12];
  const float* b_hh      = (const float*)d_in[13];
  float* out = (float*)d_out;

  char* ws = (char*)d_ws;
  size_t off = 0;
  auto take = [&](size_t bytes) {
    char* p = ws + off;
    off = (off + bytes + 255) & ~(size_t)255;
    return p;
  };
  __hip_bfloat16* C      = (__hip_bfloat16*)take((size_t)BB * NN * TT * 416 * 2);  // 79.9MB
  float* score  = (float*)take((size_t)BB * NN * TT * 4);
  float* alpha  = (float*)take((size_t)BB * NN * TT * 4);
  __hip_bfloat16* Ebf    = (__hip_bfloat16*)take((size_t)BB * NN * 416 * 2);
  __hip_bfloat16* Wih_bf = (__hip_bfloat16*)take((size_t)1344 * 416 * 2);
  float* Wpack  = (float*)take((size_t)8 * 400 * 150 * 4);
  float* gx     = (float*)take((size_t)BB * NN * 1200 * 4);
  float* h0     = (float*)take((size_t)BB * GG * 4);
  float* h1     = (float*)take((size_t)BB * GG * 4);
  __hip_bfloat16* WT2    = (__hip_bfloat16*)take((size_t)30 * 448 * 32 * 2);      // 860KB
  __hip_bfloat16* vT2    = (__hip_bfloat16*)take((size_t)13 * 224 * 32 * 2);      // 186KB
  float* qp     = (float*)take(224 * 4);
  float* vbp    = (float*)take(224 * 4);
  (void)ws_size;

  k_prep_all<<<6204, 256, 0, stream>>>(W_hh, conv_w, v, q, vb, W_ih, user_id,
                                       user_emb, Wpack, WT2, vT2, qp, vbp,
                                       Wih_bf, h0);

  k_conv<<<BB * NN / 2, 256, 0, stream>>>(title, word_emb, WT2, conv_b, C);
  k_attn<<<BB * NN * TT / 256, 512, 0, stream>>>(C, vT2, vbp, qp, score);
  k2_softmax_n<<<(BB * TT + 255) / 256, 256, 0, stream>>>(score, alpha);
  k3_wsum<<<BB * NN, 256, 0, stream>>>(alpha, C, Ebf);
  k4_gx_mfma<<<75, 512, 0, stream>>>(Ebf, Wih_bf, b_ih, gx);

  float* hbuf[2] = {h0, h1};
  for (int step = 0; step < NN; ++step) {
    k5_step<<<256, 256, 0, stream>>>(hbuf[step & 1], hbuf[(step + 1) & 1],
                                     Wpack, b_hh, gx, hist_len, out, step);
  }
}